// Round 1
// baseline (1056.073 us; speedup 1.0000x reference)
//
#include <hip/hip_runtime.h>
#include <math.h>

#define Bn 4
#define Ln 2048
#define Vn 32000

// ws layout (float offsets):
// [0..15]                  consts: 0=beta_attn, 1=beta_class
// [R_OFF .. +4*Ln)         R table: float4 (q0, q1, ba*u0, ba*u1) per position
// [S_OFF .. +4*Bn*Ln)      S: gathered token embeddings, float4 per (b,l)
// [H_OFF .. +4*Bn*Ln)      H: h_E (beta_class folded into E4), float4 per (b,l)
// [E4_OFF .. +4*Vn)        E4: beta_class * E[v], padded to float4
#define R_OFF 16
#define S_OFF (R_OFF + 4 * Ln)
#define H_OFF (S_OFF + 4 * Bn * Ln)
#define E4_OFF (H_OFF + 4 * Bn * Ln)

__global__ void setup_k(const float* __restrict__ Ppos, const float* __restrict__ M,
                        const float* __restrict__ rba, const float* __restrict__ rbc,
                        float* __restrict__ ws) {
    __shared__ float c[6];
    if (threadIdx.x == 0) {
        float ba = log1pf(expf(rba[0])) + 1e-6f;   // softplus
        float bc = log1pf(expf(rbc[0])) + 1e-6f;
        ws[0] = ba;
        ws[1] = bc;
        c[0] = ba; c[1] = bc;
        // Mp = M[3:5, 3:5] of row-major 5x5
        c[2] = M[18]; c[3] = M[19]; c[4] = M[23]; c[5] = M[24];
    }
    __syncthreads();
    const float ba = c[0];
    const float m00 = c[2], m01 = c[3], m10 = c[4], m11 = c[5];
    float4* __restrict__ R = (float4*)(ws + R_OFF);
    for (int l = threadIdx.x; l < Ln; l += blockDim.x) {
        float q0 = Ppos[2 * l], q1 = Ppos[2 * l + 1];
        // u = Mp^T q  (scores[i,j] = ba * u_i . q_j)
        float u0 = m00 * q0 + m10 * q1;
        float u1 = m01 * q0 + m11 * q1;
        R[l] = make_float4(q0, q1, ba * u0, ba * u1);
    }
}

__global__ void gather_k(const int* __restrict__ x, const float* __restrict__ E,
                         float* __restrict__ ws) {
    int i = blockIdx.x * blockDim.x + threadIdx.x;
    const float bc = ws[1];
    float4* __restrict__ S = (float4*)(ws + S_OFF);
    float4* __restrict__ E4 = (float4*)(ws + E4_OFF);
    if (i < Vn) {
        float e0 = E[3 * i], e1 = E[3 * i + 1], e2 = E[3 * i + 2];
        E4[i] = make_float4(bc * e0, bc * e1, bc * e2, 0.f);
    }
    if (i < Bn * Ln) {
        int t = x[i];
        S[i] = make_float4(E[3 * t], E[3 * t + 1], E[3 * t + 2], 0.f);
    }
}

__global__ __launch_bounds__(256) void attn_k(const float* __restrict__ Wm,
                                              float* __restrict__ ws) {
    const int i = blockIdx.x;
    const float4* __restrict__ R = (const float4*)(ws + R_OFF);
    const float4* __restrict__ S = (const float4*)(ws + S_OFF);
    float4* __restrict__ H = (float4*)(ws + H_OFF);
    const int tid = threadIdx.x;

    if (i == 0) {  // fully-masked row -> alpha row = 0 -> h = 0
        if (tid < Bn) H[tid * Ln] = make_float4(0.f, 0.f, 0.f, 0.f);
        return;
    }

    const int lane = tid & 63;
    const int wid = tid >> 6;
    __shared__ float sred[4];

    float4 ri = R[i];
    const float u0 = ri.z, u1 = ri.w;

    // pass 1: row max over strict lower triangle j < i
    float m = -INFINITY;
    for (int j = tid; j < i; j += 256) {
        float4 rj = R[j];
        m = fmaxf(m, u0 * rj.x + u1 * rj.y);
    }
#pragma unroll
    for (int o = 32; o > 0; o >>= 1) m = fmaxf(m, __shfl_down(m, o));
    if (lane == 0) sred[wid] = m;
    __syncthreads();
    m = fmaxf(fmaxf(sred[0], sred[1]), fmaxf(sred[2], sred[3]));
    __syncthreads();

    // pass 2: sum of exp + 12 weighted accumulators (4 batches x 3 dims)
    float sum = 0.f;
    float acc[Bn][3];
#pragma unroll
    for (int b = 0; b < Bn; ++b) { acc[b][0] = 0.f; acc[b][1] = 0.f; acc[b][2] = 0.f; }

    for (int j = tid; j < i; j += 256) {
        float4 rj = R[j];
        float w = expf(u0 * rj.x + u1 * rj.y - m);
        sum += w;
#pragma unroll
        for (int b = 0; b < Bn; ++b) {
            float4 sv = S[b * Ln + j];
            acc[b][0] += w * sv.x;
            acc[b][1] += w * sv.y;
            acc[b][2] += w * sv.z;
        }
    }

    auto blkSum = [&](float v) -> float {
#pragma unroll
        for (int o = 32; o > 0; o >>= 1) v += __shfl_down(v, o);
        if (lane == 0) sred[wid] = v;
        __syncthreads();
        float r = sred[0] + sred[1] + sred[2] + sred[3];
        __syncthreads();
        return r;
    };

    float tsum = blkSum(sum);
    float cs[Bn][3];
#pragma unroll
    for (int b = 0; b < Bn; ++b)
#pragma unroll
        for (int d = 0; d < 3; ++d) cs[b][d] = blkSum(acc[b][d]);

    if (tid == 0) {
        float inv = 1.0f / tsum;
#pragma unroll
        for (int b = 0; b < Bn; ++b) {
            float c0 = cs[b][0] * inv, c1 = cs[b][1] * inv, c2 = cs[b][2] * inv;
            // h = c_s[:3] @ W[:3,:3], W row-major 5x5
            float h0 = c0 * Wm[0] + c1 * Wm[5] + c2 * Wm[10];
            float h1 = c0 * Wm[1] + c1 * Wm[6] + c2 * Wm[11];
            float h2 = c0 * Wm[2] + c1 * Wm[7] + c2 * Wm[12];
            H[b * Ln + i] = make_float4(h0, h1, h2, 0.f);
        }
    }
}

// Each block: one 1024-token v-chunk (256 threads x 4 v) for 8 consecutive rows.
// E4 loaded once per block, reused across the 8 rows -> L2 read traffic / 8.
#define LROWS 8
__global__ __launch_bounds__(256) void logits_k(const float* __restrict__ ws,
                                                float* __restrict__ out) {
    const float4* __restrict__ E4 = (const float4*)(ws + E4_OFF);
    const float4* __restrict__ H = (const float4*)(ws + H_OFF);
    int vq = blockIdx.x * 256 + threadIdx.x;  // float4 group of 4 consecutive v
    if (vq >= Vn / 4) return;
    int row0 = blockIdx.y * LROWS;
    float4 e0 = E4[4 * vq + 0];
    float4 e1 = E4[4 * vq + 1];
    float4 e2 = E4[4 * vq + 2];
    float4 e3 = E4[4 * vq + 3];
#pragma unroll
    for (int r = 0; r < LROWS; ++r) {
        float4 h = H[row0 + r];
        float4 o;
        o.x = h.x * e0.x + h.y * e0.y + h.z * e0.z;
        o.y = h.x * e1.x + h.y * e1.y + h.z * e1.z;
        o.z = h.x * e2.x + h.y * e2.y + h.z * e2.z;
        o.w = h.x * e3.x + h.y * e3.y + h.z * e3.z;
        *((float4*)(out + (size_t)(row0 + r) * Vn + 4 * vq)) = o;
    }
}

extern "C" void kernel_launch(void* const* d_in, const int* in_sizes, int n_in,
                              void* d_out, int out_size, void* d_ws, size_t ws_size,
                              hipStream_t stream) {
    const int* x = (const int*)d_in[0];
    const float* E = (const float*)d_in[1];
    const float* Ppos = (const float*)d_in[2];
    const float* M = (const float*)d_in[3];
    const float* Wm = (const float*)d_in[4];
    const float* rba = (const float*)d_in[5];
    const float* rbc = (const float*)d_in[6];
    float* out = (float*)d_out;
    float* ws = (float*)d_ws;

    hipLaunchKernelGGL(setup_k, dim3(1), dim3(256), 0, stream, Ppos, M, rba, rbc, ws);
    hipLaunchKernelGGL(gather_k, dim3((Vn + 255) / 256), dim3(256), 0, stream, x, E, ws);
    hipLaunchKernelGGL(attn_k, dim3(Ln), dim3(256), 0, stream, Wm, ws);
    hipLaunchKernelGGL(logits_k, dim3((Vn / 4 + 255) / 256, (Bn * Ln) / LROWS), dim3(256), 0,
                       stream, ws, out);
}